// Round 1
// baseline (62234.613 us; speedup 1.0000x reference)
//
#include <hip/hip_runtime.h>
#include <hip/hip_bf16.h>

#define H 2048
#define T 2048
#define INPUT 1024
#define FOURH 8192

typedef __attribute__((ext_vector_type(8))) short bf16x8;
typedef __attribute__((ext_vector_type(4))) float f32x4_t;

__device__ __forceinline__ short f2bf(float f) {
  union { float f; unsigned u; } v; v.f = f;
  unsigned r = v.u + 0x7FFFu + ((v.u >> 16) & 1u);
  return (short)(r >> 16);
}

// ---------------- prep: bf16 conversions + dt_prev table + barrier init ----------------
__global__ void prep_kernel(const float* __restrict__ x, const float* __restrict__ W_ih,
                            const float* __restrict__ time_, short* __restrict__ xb,
                            short* __restrict__ wb, float* __restrict__ dtp,
                            unsigned* __restrict__ bar) {
  size_t i = (size_t)blockIdx.x * blockDim.x + threadIdx.x;
  size_t stride = (size_t)gridDim.x * blockDim.x;
  if (i < (size_t)T * INPUT) xb[i] = f2bf(x[i]);
  for (size_t j = i; j < (size_t)FOURH * INPUT; j += stride) wb[j] = f2bf(W_ih[j]);
  if (i < T) dtp[i] = (i >= 2) ? (time_[i - 1] - time_[i - 2]) : 0.0f;
  if (i == 0) { bar[0] = 0u; bar[1] = 0u; }
}

// ---------------- xg GEMM: C[m][n] = sum_k x[m][k] * W_ih[n][k] + b_ih[n] + b_hh[n] ----
// M=2048, N=8192, K=1024. mfma_f32_16x16x32_bf16:
//   A frag: A[m=lane&15][k=(lane>>4)*8+j]; B frag: B[k=(lane>>4)*8+j][n=lane&15]
//   C/D:    D[row=(lane>>4)*4+r][col=lane&15]
__global__ void __launch_bounds__(256)
gemm_xg(const short* __restrict__ A, const short* __restrict__ B,
        const float* __restrict__ b_ih, const float* __restrict__ b_hh,
        float* __restrict__ xg) {
  int wave = threadIdx.x >> 6;
  int lane = threadIdx.x & 63;
  int m0 = blockIdx.y << 4;
  int n0 = (blockIdx.x << 6) + (wave << 4);
  int r16 = lane & 15, q = lane >> 4;
  const short* ap = A + (size_t)(m0 + r16) * INPUT + q * 8;
  const short* bp = B + (size_t)(n0 + r16) * INPUT + q * 8;
  f32x4_t acc = {0.f, 0.f, 0.f, 0.f};
#pragma unroll 4
  for (int k = 0; k < INPUT; k += 32) {
    bf16x8 av = *(const bf16x8*)(ap + k);
    bf16x8 bv = *(const bf16x8*)(bp + k);
    acc = __builtin_amdgcn_mfma_f32_16x16x32_bf16(av, bv, acc, 0, 0, 0);
  }
  int n = n0 + r16;
  float bias = b_ih[n] + b_hh[n];
#pragma unroll
  for (int r = 0; r < 4; ++r) {
    int m = m0 + q * 4 + r;
    xg[(size_t)m * FOURH + n] = acc[r] + bias;
  }
}

// ---------------- device-scope sense-reversing grid barrier ----------------
__device__ __forceinline__ void gridbar(unsigned* bar, unsigned nblk) {
  __syncthreads();
  if (threadIdx.x == 0) {
    unsigned gen = __hip_atomic_load(&bar[1], __ATOMIC_RELAXED, __HIP_MEMORY_SCOPE_AGENT);
    unsigned a = __hip_atomic_fetch_add(&bar[0], 1u, __ATOMIC_ACQ_REL, __HIP_MEMORY_SCOPE_AGENT);
    if (a == nblk - 1u) {
      __hip_atomic_store(&bar[0], 0u, __ATOMIC_RELAXED, __HIP_MEMORY_SCOPE_AGENT);
      __hip_atomic_store(&bar[1], gen + 1u, __ATOMIC_RELEASE, __HIP_MEMORY_SCOPE_AGENT);
    } else {
      while (__hip_atomic_load(&bar[1], __ATOMIC_ACQUIRE, __HIP_MEMORY_SCOPE_AGENT) == gen) {
        __builtin_amdgcn_s_sleep(1);
      }
    }
  }
  __syncthreads();
}

// ---------------- persistent recurrence: W_hh in registers ----------------
// 256 blocks x 512 thr (8 waves). wave w of block b owns hidden unit u = 8b+w:
// gate rows {u, H+u, 2H+u, 3H+u}. lane l holds cols [32l,32l+32) of each row.
__global__ void __launch_bounds__(512, 2)
lstm_rec(const float* __restrict__ xg, const float* __restrict__ W_hh,
         const float* __restrict__ decay_w, const float* __restrict__ decay_b,
         const float* __restrict__ h0, const float* __restrict__ c0,
         const float* __restrict__ dtp, float* __restrict__ hs,
         float* __restrict__ hbuf, unsigned* bar) {
  const int wave = threadIdx.x >> 6;
  const int lane = threadIdx.x & 63;
  const int u = (blockIdx.x << 3) + wave;

  float wreg[4][32];
#pragma unroll
  for (int g = 0; g < 4; ++g) {
    const float* wr = W_hh + (size_t)(g * H + u) * H + lane * 32;
#pragma unroll
    for (int j = 0; j < 32; j += 4)
      *(f32x4_t*)&wreg[g][j] = *(const f32x4_t*)(wr + j);
  }
  const float dw = decay_w[u], db = decay_b[u];
  float c = c0[u];
  if (lane == 0) hbuf[u] = h0[u];  // gamma[0] = 1
  gridbar(bar, gridDim.x);

  for (int t = 0; t < T; ++t) {
    const f32x4_t* hb = (const f32x4_t*)(hbuf + ((t & 1) << 11)) + (lane << 3);
    float hreg[32];
#pragma unroll
    for (int q = 0; q < 8; ++q) *(f32x4_t*)&hreg[q * 4] = hb[q];
    float a0 = 0.f, a1 = 0.f, a2 = 0.f, a3 = 0.f;
#pragma unroll
    for (int j = 0; j < 32; ++j) {
      a0 += wreg[0][j] * hreg[j];
      a1 += wreg[1][j] * hreg[j];
      a2 += wreg[2][j] * hreg[j];
      a3 += wreg[3][j] * hreg[j];
    }
#pragma unroll
    for (int s = 32; s >= 1; s >>= 1) {
      a0 += __shfl_xor(a0, s);
      a1 += __shfl_xor(a1, s);
      a2 += __shfl_xor(a2, s);
      a3 += __shfl_xor(a3, s);
    }
    if (lane == 0) {
      const float* xr = xg + (size_t)t * FOURH;
      float iv = a0 + xr[u];
      float fv = a1 + xr[H + u];
      float gv = a2 + xr[2 * H + u];
      float ov = a3 + xr[3 * H + u];
      iv = 1.f / (1.f + __expf(-iv));
      fv = 1.f / (1.f + __expf(-fv));
      gv = tanhf(gv);
      ov = 1.f / (1.f + __expf(-ov));
      c = fv * c + iv * gv;
      float h = ov * tanhf(c);
      hs[(size_t)t * H + u] = h;                       // pristine h for attention
      if (t + 1 < T) {                                  // producer-side gamma
        float gam = __expf(-fmaxf(0.f, dtp[t + 1] * dw + db));
        hbuf[(((t + 1) & 1) << 11) + u] = h * gam;
      }
    }
    gridbar(bar, gridDim.x);
  }
}

// ---------------- attention pooling ----------------
__global__ void attn_k(const float* __restrict__ hs, float* __restrict__ attn) {
  int t = blockIdx.x;
  const float* row = hs + (size_t)t * H;
  const float* hf = hs + (size_t)(T - 1) * H;
  float s = 0.f;
  for (int i = threadIdx.x; i < H; i += 256) s += row[i] * hf[i];
#pragma unroll
  for (int o = 32; o; o >>= 1) s += __shfl_down(s, o);
  __shared__ float wsum[4];
  if ((threadIdx.x & 63) == 0) wsum[threadIdx.x >> 6] = s;
  __syncthreads();
  if (threadIdx.x == 0) attn[t] = wsum[0] + wsum[1] + wsum[2] + wsum[3];
}

__global__ void softmax_k(float* __restrict__ a) {
  int tid = threadIdx.x;
  __shared__ float red[16];
  __shared__ float bcast;
  float m = -1e30f;
  for (int i = tid; i < T; i += 1024) m = fmaxf(m, a[i]);
#pragma unroll
  for (int o = 32; o; o >>= 1) m = fmaxf(m, __shfl_xor(m, o));
  if ((tid & 63) == 0) red[tid >> 6] = m;
  __syncthreads();
  if (tid == 0) {
    float mm = red[0];
    for (int i = 1; i < 16; ++i) mm = fmaxf(mm, red[i]);
    bcast = mm;
  }
  __syncthreads();
  float M = bcast, s = 0.f;
  for (int i = tid; i < T; i += 1024) { float e = __expf(a[i] - M); a[i] = e; s += e; }
#pragma unroll
  for (int o = 32; o; o >>= 1) s += __shfl_xor(s, o);
  if ((tid & 63) == 0) red[tid >> 6] = s;
  __syncthreads();
  if (tid == 0) {
    float ss = 0.f;
    for (int i = 0; i < 16; ++i) ss += red[i];
    bcast = 1.f / ss;
  }
  __syncthreads();
  float inv = bcast;
  for (int i = tid; i < T; i += 1024) a[i] *= inv;
}

__global__ void ctx_k(const float* __restrict__ hs, const float* __restrict__ w,
                      float* __restrict__ out) {
  int h = (blockIdx.x << 8) + threadIdx.x;
  int t0 = blockIdx.y << 6;
  float acc = 0.f;
  for (int t = t0; t < t0 + 64; ++t) acc += w[t] * hs[(size_t)t * H + h];
  atomicAdd(&out[h], acc);
}

// ---------------- launch ----------------
extern "C" void kernel_launch(void* const* d_in, const int* in_sizes, int n_in,
                              void* d_out, int out_size, void* d_ws, size_t ws_size,
                              hipStream_t stream) {
  const float* x       = (const float*)d_in[0];
  const float* time_   = (const float*)d_in[1];
  const float* W_ih    = (const float*)d_in[2];
  const float* W_hh    = (const float*)d_in[3];
  const float* b_ih    = (const float*)d_in[4];
  const float* b_hh    = (const float*)d_in[5];
  const float* decay_w = (const float*)d_in[6];
  const float* decay_b = (const float*)d_in[7];
  const float* h0      = (const float*)d_in[8];
  const float* c0      = (const float*)d_in[9];

  char* ws = (char*)d_ws;
  float*    xg   = (float*)ws;                          // 64 MB  [T][4H]
  float*    hs   = (float*)(ws + (64u << 20));          // 16 MB  [T][H]
  short*    xb   = (short*)(ws + (80u << 20));          // 4 MB
  short*    wb   = (short*)(ws + (84u << 20));          // 16 MB
  float*    hbuf = (float*)(ws + (100u << 20));         // 2 x H double buffer
  float*    dtp  = hbuf + 2 * H;
  float*    attn = dtp + T;
  unsigned* bar  = (unsigned*)(attn + T);

  prep_kernel<<<8192, 256, 0, stream>>>(x, W_ih, time_, xb, wb, dtp, bar);

  dim3 g1(FOURH / 64, T / 16);
  gemm_xg<<<g1, 256, 0, stream>>>(xb, wb, b_ih, b_hh, xg);

  {
    void* args[] = {&xg, (void*)&W_hh, (void*)&decay_w, (void*)&decay_b,
                    (void*)&h0, (void*)&c0, &dtp, &hs, &hbuf, &bar};
    hipLaunchCooperativeKernel((void*)lstm_rec, dim3(256), dim3(512), args, 0, stream);
  }

  attn_k<<<T, 256, 0, stream>>>(hs, attn);
  softmax_k<<<1, 1024, 0, stream>>>(attn);
  hipMemsetAsync(d_out, 0, out_size * sizeof(float), stream);
  ctx_k<<<dim3(H / 256, T / 64), 256, 0, stream>>>(hs, attn, (float*)d_out);
}

// Round 3
// 46406.311 us; speedup vs baseline: 1.3411x; 1.3411x over previous
//
#include <hip/hip_runtime.h>
#include <hip/hip_bf16.h>

#define H 2048
#define T 2048
#define INPUT 1024
#define FOURH 8192
#define NBLK 256

typedef __attribute__((ext_vector_type(8))) short bf16x8;
typedef __attribute__((ext_vector_type(4))) float f32x4_t;

__device__ __forceinline__ short f2bf(float f) {
  union { float f; unsigned u; } v; v.f = f;
  unsigned r = v.u + 0x7FFFu + ((v.u >> 16) & 1u);
  return (short)(r >> 16);
}

// ---------------- prep: bf16 conversions + dt_prev table + flag init ----------------
__global__ void prep_kernel(const float* __restrict__ x, const float* __restrict__ W_ih,
                            const float* __restrict__ time_, short* __restrict__ xb,
                            short* __restrict__ wb, float* __restrict__ dtp,
                            unsigned* __restrict__ flags) {
  size_t i = (size_t)blockIdx.x * blockDim.x + threadIdx.x;
  size_t stride = (size_t)gridDim.x * blockDim.x;
  if (i < (size_t)T * INPUT) xb[i] = f2bf(x[i]);
  for (size_t j = i; j < (size_t)FOURH * INPUT; j += stride) wb[j] = f2bf(W_ih[j]);
  if (i < T) dtp[i] = (i >= 2) ? (time_[i - 1] - time_[i - 2]) : 0.0f;
  if (i < NBLK) flags[i] = 0u;
}

// ---------------- xg GEMM: C[m][n] = sum_k x[m][k] * W_ih[n][k] + b_ih[n] + b_hh[n] ----
__global__ void __launch_bounds__(256)
gemm_xg(const short* __restrict__ A, const short* __restrict__ B,
        const float* __restrict__ b_ih, const float* __restrict__ b_hh,
        float* __restrict__ xg) {
  int wave = threadIdx.x >> 6;
  int lane = threadIdx.x & 63;
  int m0 = blockIdx.y << 4;
  int n0 = (blockIdx.x << 6) + (wave << 4);
  int r16 = lane & 15, q = lane >> 4;
  const short* ap = A + (size_t)(m0 + r16) * INPUT + q * 8;
  const short* bp = B + (size_t)(n0 + r16) * INPUT + q * 8;
  f32x4_t acc = {0.f, 0.f, 0.f, 0.f};
#pragma unroll 4
  for (int k = 0; k < INPUT; k += 32) {
    bf16x8 av = *(const bf16x8*)(ap + k);
    bf16x8 bv = *(const bf16x8*)(bp + k);
    acc = __builtin_amdgcn_mfma_f32_16x16x32_bf16(av, bv, acc, 0, 0, 0);
  }
  int n = n0 + r16;
  float bias = b_ih[n] + b_hh[n];
#pragma unroll
  for (int r = 0; r < 4; ++r) {
    int m = m0 + q * 4 + r;
    xg[(size_t)m * FOURH + n] = acc[r] + bias;
  }
}

// ---------------- contention-free epoch barrier ----------------
// Each block release-stores its own flag = e (no RMW, no shared-cacheline RMW
// serialization). Every block's threads 0..NBLK-1 poll all flags in parallel
// (all-to-all: removes the gather->publish double hop). Epoch is monotone, so
// flags never need resetting.
__device__ __forceinline__ void epoch_bar(volatile unsigned* flags, unsigned e) {
  __syncthreads();
  if (threadIdx.x == 0)
    __hip_atomic_store((unsigned*)&flags[blockIdx.x], e, __ATOMIC_RELEASE,
                       __HIP_MEMORY_SCOPE_AGENT);
  if (threadIdx.x < NBLK) {
    while (__hip_atomic_load((unsigned*)&flags[threadIdx.x], __ATOMIC_RELAXED,
                             __HIP_MEMORY_SCOPE_AGENT) < e) {
    }
  }
  __builtin_amdgcn_fence(__ATOMIC_ACQUIRE, "agent");
  __syncthreads();
}

// ---------------- persistent recurrence: W_hh in registers ----------------
// 256 blocks x 512 thr (8 waves, 1 block/CU). wave w of block b owns hidden
// unit u = 8b+w: gate rows {u, H+u, 2H+u, 3H+u}; lane l holds cols [32l,32l+32).
__global__ void __launch_bounds__(512, 2)
lstm_rec(const float* __restrict__ xg, const float* __restrict__ W_hh,
         const float* __restrict__ decay_w, const float* __restrict__ decay_b,
         const float* __restrict__ h0, const float* __restrict__ c0,
         const float* __restrict__ dtp, float* __restrict__ hs,
         float* __restrict__ hbuf, unsigned* flags) {
  const int wave = threadIdx.x >> 6;
  const int lane = threadIdx.x & 63;
  const int u = (blockIdx.x << 3) + wave;

  float wreg[4][32];
#pragma unroll
  for (int g = 0; g < 4; ++g) {
    const float* wr = W_hh + (size_t)(g * H + u) * H + lane * 32;
#pragma unroll
    for (int j = 0; j < 32; j += 4)
      *(f32x4_t*)&wreg[g][j] = *(const f32x4_t*)(wr + j);
  }
  const float dw = decay_w[u], db = decay_b[u];
  float c = c0[u];
  if (lane == 0) hbuf[u] = h0[u];  // gamma[0] = 1
  epoch_bar(flags, 1u);

  for (int t = 0; t < T; ++t) {
    const f32x4_t* hb = (const f32x4_t*)(hbuf + ((t & 1) << 11)) + (lane << 3);
    float hreg[32];
#pragma unroll
    for (int q = 0; q < 8; ++q) *(f32x4_t*)&hreg[q * 4] = hb[q];
    float a0 = 0.f, a1 = 0.f, a2 = 0.f, a3 = 0.f;
#pragma unroll
    for (int j = 0; j < 32; ++j) {
      a0 += wreg[0][j] * hreg[j];
      a1 += wreg[1][j] * hreg[j];
      a2 += wreg[2][j] * hreg[j];
      a3 += wreg[3][j] * hreg[j];
    }
#pragma unroll
    for (int s = 32; s >= 1; s >>= 1) {
      a0 += __shfl_xor(a0, s);
      a1 += __shfl_xor(a1, s);
      a2 += __shfl_xor(a2, s);
      a3 += __shfl_xor(a3, s);
    }
    if (lane == 0) {
      const float* xr = xg + (size_t)t * FOURH;
      float iv = a0 + xr[u];
      float fv = a1 + xr[H + u];
      float gv = a2 + xr[2 * H + u];
      float ov = a3 + xr[3 * H + u];
      iv = 1.f / (1.f + __expf(-iv));
      fv = 1.f / (1.f + __expf(-fv));
      gv = tanhf(gv);
      ov = 1.f / (1.f + __expf(-ov));
      c = fv * c + iv * gv;
      float h = ov * tanhf(c);
      hs[(size_t)t * H + u] = h;                       // pristine h for attention
      if (t + 1 < T) {                                  // producer-side gamma
        float gam = __expf(-fmaxf(0.f, dtp[t + 1] * dw + db));
        hbuf[(((t + 1) & 1) << 11) + u] = h * gam;
      }
    }
    epoch_bar(flags, (unsigned)t + 2u);
  }
}

// ---------------- attention pooling ----------------
__global__ void attn_k(const float* __restrict__ hs, float* __restrict__ attn) {
  int t = blockIdx.x;
  const float* row = hs + (size_t)t * H;
  const float* hf = hs + (size_t)(T - 1) * H;
  float s = 0.f;
  for (int i = threadIdx.x; i < H; i += 256) s += row[i] * hf[i];
#pragma unroll
  for (int o = 32; o; o >>= 1) s += __shfl_down(s, o);
  __shared__ float wsum[4];
  if ((threadIdx.x & 63) == 0) wsum[threadIdx.x >> 6] = s;
  __syncthreads();
  if (threadIdx.x == 0) attn[t] = wsum[0] + wsum[1] + wsum[2] + wsum[3];
}

__global__ void softmax_k(float* __restrict__ a) {
  int tid = threadIdx.x;
  __shared__ float red[16];
  __shared__ float bcast;
  float m = -1e30f;
  for (int i = tid; i < T; i += 1024) m = fmaxf(m, a[i]);
#pragma unroll
  for (int o = 32; o; o >>= 1) m = fmaxf(m, __shfl_xor(m, o));
  if ((tid & 63) == 0) red[tid >> 6] = m;
  __syncthreads();
  if (tid == 0) {
    float mm = red[0];
    for (int i = 1; i < 16; ++i) mm = fmaxf(mm, red[i]);
    bcast = mm;
  }
  __syncthreads();
  float M = bcast, s = 0.f;
  for (int i = tid; i < T; i += 1024) { float e = __expf(a[i] - M); a[i] = e; s += e; }
#pragma unroll
  for (int o = 32; o; o >>= 1) s += __shfl_xor(s, o);
  if ((tid & 63) == 0) red[tid >> 6] = s;
  __syncthreads();
  if (tid == 0) {
    float ss = 0.f;
    for (int i = 0; i < 16; ++i) ss += red[i];
    bcast = 1.f / ss;
  }
  __syncthreads();
  float inv = bcast;
  for (int i = tid; i < T; i += 1024) a[i] *= inv;
}

__global__ void ctx_k(const float* __restrict__ hs, const float* __restrict__ w,
                      float* __restrict__ out) {
  int h = (blockIdx.x << 8) + threadIdx.x;
  int t0 = blockIdx.y << 6;
  float acc = 0.f;
  for (int t = t0; t < t0 + 64; ++t) acc += w[t] * hs[(size_t)t * H + h];
  atomicAdd(&out[h], acc);
}

// ---------------- launch ----------------
extern "C" void kernel_launch(void* const* d_in, const int* in_sizes, int n_in,
                              void* d_out, int out_size, void* d_ws, size_t ws_size,
                              hipStream_t stream) {
  const float* x       = (const float*)d_in[0];
  const float* time_   = (const float*)d_in[1];
  const float* W_ih    = (const float*)d_in[2];
  const float* W_hh    = (const float*)d_in[3];
  const float* b_ih    = (const float*)d_in[4];
  const float* b_hh    = (const float*)d_in[5];
  const float* decay_w = (const float*)d_in[6];
  const float* decay_b = (const float*)d_in[7];
  const float* h0      = (const float*)d_in[8];
  const float* c0      = (const float*)d_in[9];

  char* ws = (char*)d_ws;
  float*    xg   = (float*)ws;                          // 64 MB  [T][4H]
  float*    hs   = (float*)(ws + (64u << 20));          // 16 MB  [T][H]
  short*    xb   = (short*)(ws + (80u << 20));          // 4 MB
  short*    wb   = (short*)(ws + (84u << 20));          // 16 MB
  float*    hbuf = (float*)(ws + (100u << 20));         // 2 x H double buffer
  float*    dtp  = hbuf + 2 * H;
  float*    attn = dtp + T;
  unsigned* flags = (unsigned*)(attn + T);

  prep_kernel<<<8192, 256, 0, stream>>>(x, W_ih, time_, xb, wb, dtp, flags);

  dim3 g1(FOURH / 64, T / 16);
  gemm_xg<<<g1, 256, 0, stream>>>(xb, wb, b_ih, b_hh, xg);

  {
    void* args[] = {&xg, (void*)&W_hh, (void*)&decay_w, (void*)&decay_b,
                    (void*)&h0, (void*)&c0, &dtp, &hs, &hbuf, &flags};
    (void)hipLaunchCooperativeKernel((void*)lstm_rec, dim3(NBLK), dim3(512), args, 0, stream);
  }

  attn_k<<<T, 256, 0, stream>>>(hs, attn);
  softmax_k<<<1, 1024, 0, stream>>>(attn);
  (void)hipMemsetAsync(d_out, 0, out_size * sizeof(float), stream);
  ctx_k<<<dim3(H / 256, T / 64), 256, 0, stream>>>(hs, attn, (float*)d_out);
}